// Round 1
// baseline (305.374 us; speedup 1.0000x reference)
//
#include <hip/hip_runtime.h>
#include <hip/hip_bf16.h>

typedef __bf16 bf16x8 __attribute__((ext_vector_type(8)));
typedef float f32x4 __attribute__((ext_vector_type(4)));
typedef unsigned short ushort_t;
typedef ushort_t ushort8 __attribute__((ext_vector_type(8)));
typedef unsigned uint2v __attribute__((ext_vector_type(2)));
typedef unsigned uint4v __attribute__((ext_vector_type(4)));

#define DIM 512
#define HEADS 8
#define HD 64
#define HWN 4096   // 64*64 queries per batch
#define KVN 1024   // 32*32 kv tokens per batch
#define KKV 2048   // 512*2*2 im2col K for the strided conv
#define LOG2E 1.44269504f

__device__ __forceinline__ ushort_t f2bf(float f) {
    union { float f; unsigned u; } v; v.f = f;
    unsigned r = v.u + 0x7fffu + ((v.u >> 16) & 1u);
    return (ushort_t)(r >> 16);
}

// pack two f32 -> one dword of 2 bf16 (RNE), low16 = lo
__device__ __forceinline__ unsigned cvtpk(float lo, float hi) {
    unsigned r;
    asm("v_cvt_pk_bf16_f32 %0, %1, %2" : "=v"(r) : "v"(lo), "v"(hi));
    return r;
}

// v_permlane32_swap_b32: a' = [a.lo32, b.lo32], b' = [a.hi32, b.hi32]
__device__ __forceinline__ void pl32swap(unsigned &a, unsigned &b) {
    asm("v_permlane32_swap_b32 %0, %1" : "+v"(a), "+v"(b));
}
// v_permlane16_swap_b32: a' = [a.g0, b.g0, a.g2, b.g2], b' = [a.g1, b.g1, a.g3, b.g3]
__device__ __forceinline__ void pl16swap(unsigned &a, unsigned &b) {
    asm("v_permlane16_swap_b32 %0, %1" : "+v"(a), "+v"(b));
}

__device__ __forceinline__ bf16x8 frag4(unsigned a, unsigned b, unsigned c, unsigned d) {
    uint4v t; t[0] = a; t[1] = b; t[2] = c; t[3] = d;
    return __builtin_bit_cast(bf16x8, t);
}

// ---------------------------------------------------------------------------
// Kernel 0a: small f32 -> bf16 convert (wq, wout)
// ---------------------------------------------------------------------------
__global__ __launch_bounds__(256) void cvt_kernel(
        const float* __restrict__ src, ushort_t* __restrict__ dst, int n8) {
    int i = blockIdx.x * 256 + threadIdx.x;
    if (i >= n8) return;
    const float* p = &src[(size_t)i * 8];
    f32x4 v0 = *(const f32x4*)&p[0];
    f32x4 v1 = *(const f32x4*)&p[4];
    ushort8 w;
    w[0] = f2bf(v0[0]); w[1] = f2bf(v0[1]); w[2] = f2bf(v0[2]); w[3] = f2bf(v0[3]);
    w[4] = f2bf(v1[0]); w[5] = f2bf(v1[1]); w[6] = f2bf(v1[2]); w[7] = f2bf(v1[3]);
    *(ushort8*)&dst[i * 8] = w;
}

// ---------------------------------------------------------------------------
// Kernel 0b: x f32 [b][c][p] -> xT bf16 [b][p][c]   (tiled 64x64 transpose)
// ---------------------------------------------------------------------------
__global__ __launch_bounds__(256) void cvt_xT_kernel(
        const float* __restrict__ x, ushort_t* __restrict__ xT) {
    const int b  = blockIdx.z;
    const int c0 = blockIdx.y * 64;
    const int p0 = blockIdx.x * 64;
    __shared__ ushort_t tile[64 * 72];

    const int tid = threadIdx.x;
    {   // load + convert: each thread 16 floats of one c-row
        int r = tid >> 2, pc = (tid & 3) * 16;
        const float* src = &x[((size_t)b * DIM + c0 + r) * HWN + p0 + pc];
        f32x4 v0 = *(const f32x4*)&src[0];
        f32x4 v1 = *(const f32x4*)&src[4];
        f32x4 v2 = *(const f32x4*)&src[8];
        f32x4 v3 = *(const f32x4*)&src[12];
        ushort8 w0, w1;
        w0[0]=f2bf(v0[0]); w0[1]=f2bf(v0[1]); w0[2]=f2bf(v0[2]); w0[3]=f2bf(v0[3]);
        w0[4]=f2bf(v1[0]); w0[5]=f2bf(v1[1]); w0[6]=f2bf(v1[2]); w0[7]=f2bf(v1[3]);
        w1[0]=f2bf(v2[0]); w1[1]=f2bf(v2[1]); w1[2]=f2bf(v2[2]); w1[3]=f2bf(v2[3]);
        w1[4]=f2bf(v3[0]); w1[5]=f2bf(v3[1]); w1[6]=f2bf(v3[2]); w1[7]=f2bf(v3[3]);
        *(ushort8*)&tile[r * 72 + pc]     = w0;
        *(ushort8*)&tile[r * 72 + pc + 8] = w1;
    }
    __syncthreads();
    {   // write transposed: each thread 16 c-values of one p-row
        int p = tid >> 2, cc = (tid & 3) * 16;
        ushort8 w0, w1;
        #pragma unroll
        for (int j = 0; j < 8; ++j) {
            w0[j] = tile[(cc + j) * 72 + p];
            w1[j] = tile[(cc + 8 + j) * 72 + p];
        }
        ushort_t* dst = &xT[((size_t)b * HWN + p0 + p) * DIM + c0 + cc];
        *(ushort8*)&dst[0] = w0;
        *(ushort8*)&dst[8] = w1;
    }
}

// ---------------------------------------------------------------------------
// Kernel 0c: wkv f32 [o2][c][di][dj] -> wkvT bf16 [o2][(di*2+dj)*512 + c]
// ---------------------------------------------------------------------------
__global__ __launch_bounds__(256) void cvt_wkvT_kernel(
        const float* __restrict__ wkv, ushort_t* __restrict__ wkvT) {
    int i = blockIdx.x * 256 + threadIdx.x;     // (o2, c) pair
    if (i >= 1024 * 512) return;
    int o2 = i >> 9, c = i & 511;
    f32x4 v = *(const f32x4*)&wkv[(size_t)i * 4];  // the 4 q values for this (o2,c)
    #pragma unroll
    for (int q = 0; q < 4; ++q)
        wkvT[(size_t)o2 * KKV + q * 512 + c] = f2bf(v[q]);
}

// ---------------------------------------------------------------------------
// Kernel 1: Q projection.  Qs[b][o][p] = 0.125 * sum_c Wq[o][c] * X[c][p]
// ---------------------------------------------------------------------------
__global__ __launch_bounds__(256) void qproj_kernel(
        const ushort_t* __restrict__ xT, const ushort_t* __restrict__ wqb,
        ushort_t* __restrict__ qs) {
    const int b  = blockIdx.z;
    const int m0 = blockIdx.y * 64;
    const int p0 = blockIdx.x * 64;

    __shared__ ushort_t ldsA[64 * 40];
    __shared__ ushort_t ldsB[64 * 40];

    const int tid  = threadIdx.x;
    const int wave = tid >> 6;
    const int lane = tid & 63;
    const int l15  = lane & 15;
    const int quad = lane >> 4;
    const int mw   = (wave >> 1) * 32;
    const int nw   = (wave & 1) * 32;

    f32x4 zero = {0.f, 0.f, 0.f, 0.f};
    f32x4 acc[2][2] = {{zero, zero}, {zero, zero}};

    for (int k0 = 0; k0 < DIM; k0 += 32) {
        int row = tid >> 2, ko = (tid & 3) * 8;
        *(ushort8*)&ldsA[row * 40 + ko] =
            *(const ushort8*)&wqb[(m0 + row) * DIM + k0 + ko];
        *(ushort8*)&ldsB[row * 40 + ko] =
            *(const ushort8*)&xT[((size_t)b * HWN + p0 + row) * DIM + k0 + ko];
        __syncthreads();
        bf16x8 a0 = *(const bf16x8*)&ldsA[(mw + l15) * 40 + quad * 8];
        bf16x8 a1 = *(const bf16x8*)&ldsA[(mw + 16 + l15) * 40 + quad * 8];
        bf16x8 b0 = *(const bf16x8*)&ldsB[(nw + l15) * 40 + quad * 8];
        bf16x8 b1 = *(const bf16x8*)&ldsB[(nw + 16 + l15) * 40 + quad * 8];
        acc[0][0] = __builtin_amdgcn_mfma_f32_16x16x32_bf16(a0, b0, acc[0][0], 0, 0, 0);
        acc[0][1] = __builtin_amdgcn_mfma_f32_16x16x32_bf16(a0, b1, acc[0][1], 0, 0, 0);
        acc[1][0] = __builtin_amdgcn_mfma_f32_16x16x32_bf16(a1, b0, acc[1][0], 0, 0, 0);
        acc[1][1] = __builtin_amdgcn_mfma_f32_16x16x32_bf16(a1, b1, acc[1][1], 0, 0, 0);
        __syncthreads();
    }

    #pragma unroll
    for (int mi = 0; mi < 2; ++mi)
        #pragma unroll
        for (int ni = 0; ni < 2; ++ni)
            #pragma unroll
            for (int r = 0; r < 4; ++r) {
                int m = m0 + mw + mi * 16 + quad * 4 + r;
                int n = p0 + nw + ni * 16 + l15;
                qs[((size_t)b * DIM + m) * HWN + n] = f2bf(acc[mi][ni][r] * 0.125f);
            }
}

// ---------------------------------------------------------------------------
// Kernel 2: KV conv-GEMM with k' = (q=di*2+dj, c) ordering.
// ---------------------------------------------------------------------------
__global__ __launch_bounds__(256) void kv_kernel(
        const ushort_t* __restrict__ xT, const ushort_t* __restrict__ wkvT,
        ushort_t* __restrict__ ks, ushort_t* __restrict__ vt) {
    const int b  = blockIdx.z;
    const int m0 = blockIdx.y * 64;
    const int j0 = blockIdx.x * 64;

    __shared__ ushort_t ldsA[64 * 40];
    __shared__ ushort_t ldsB[64 * 40];
    __shared__ ushort_t cbuf[64 * 72];

    const int tid  = threadIdx.x;
    const int wave = tid >> 6;
    const int lane = tid & 63;
    const int l15  = lane & 15;
    const int quad = lane >> 4;
    const int mw   = (wave >> 1) * 32;
    const int nw   = (wave & 1) * 32;

    f32x4 zero = {0.f, 0.f, 0.f, 0.f};
    f32x4 acc[2][2] = {{zero, zero}, {zero, zero}};

    const int row = tid >> 2, ko = (tid & 3) * 8;
    const int yj = (j0 + row) >> 5, xj = (j0 + row) & 31;

    for (int k0 = 0; k0 < KKV; k0 += 32) {
        int q  = k0 >> 9;                  // (di,dj) block
        int c0 = k0 & 511;
        int di = q >> 1, dj = q & 1;
        int p  = (2 * yj + di) * 64 + 2 * xj + dj;
        *(ushort8*)&ldsA[row * 40 + ko] =
            *(const ushort8*)&wkvT[(size_t)(m0 + row) * KKV + k0 + ko];
        *(ushort8*)&ldsB[row * 40 + ko] =
            *(const ushort8*)&xT[((size_t)b * HWN + p) * DIM + c0 + ko];
        __syncthreads();
        bf16x8 a0 = *(const bf16x8*)&ldsA[(mw + l15) * 40 + quad * 8];
        bf16x8 a1 = *(const bf16x8*)&ldsA[(mw + 16 + l15) * 40 + quad * 8];
        bf16x8 b0 = *(const bf16x8*)&ldsB[(nw + l15) * 40 + quad * 8];
        bf16x8 b1 = *(const bf16x8*)&ldsB[(nw + 16 + l15) * 40 + quad * 8];
        acc[0][0] = __builtin_amdgcn_mfma_f32_16x16x32_bf16(a0, b0, acc[0][0], 0, 0, 0);
        acc[0][1] = __builtin_amdgcn_mfma_f32_16x16x32_bf16(a0, b1, acc[0][1], 0, 0, 0);
        acc[1][0] = __builtin_amdgcn_mfma_f32_16x16x32_bf16(a1, b0, acc[1][0], 0, 0, 0);
        acc[1][1] = __builtin_amdgcn_mfma_f32_16x16x32_bf16(a1, b1, acc[1][1], 0, 0, 0);
        __syncthreads();
    }

    if (m0 < DIM) {
        int h = m0 >> 6;
        #pragma unroll
        for (int mi = 0; mi < 2; ++mi)
            #pragma unroll
            for (int ni = 0; ni < 2; ++ni)
                #pragma unroll
                for (int r = 0; r < 4; ++r) {
                    int m = mw + mi * 16 + quad * 4 + r;
                    int n = nw + ni * 16 + l15;
                    cbuf[n * 72 + m] = f2bf(acc[mi][ni][r]);
                }
        __syncthreads();
        int n = tid >> 2, mo = (tid & 3) * 16;
        ushort8 v0 = *(const ushort8*)&cbuf[n * 72 + mo];
        ushort8 v1 = *(const ushort8*)&cbuf[n * 72 + mo + 8];
        ushort_t* dst = &ks[(((size_t)b * HEADS + h) * KVN + j0 + n) * HD + mo];
        *(ushort8*)&dst[0] = v0;
        *(ushort8*)&dst[8] = v1;
    } else {
        int h = (m0 - DIM) >> 6;
        #pragma unroll
        for (int mi = 0; mi < 2; ++mi)
            #pragma unroll
            for (int ni = 0; ni < 2; ++ni)
                #pragma unroll
                for (int r = 0; r < 4; ++r) {
                    int dd = mw + mi * 16 + quad * 4 + r;
                    int n  = nw + ni * 16 + l15;
                    vt[(((size_t)b * HEADS + h) * HD + dd) * KVN + j0 + n] =
                        f2bf(acc[mi][ni][r]);
                }
    }
}

// ---------------------------------------------------------------------------
// Kernel 3: attention — LDS-free, in-register softmax (swapped QK^T + permlane).
//
// S^T = mfma(K, Q):   out col = l15 = i,  row = quad*4+r = j_local(nt tile)
// P packed via v_cvt_pk_bf16_f32 (j2 = nt*8 + quad*2 + rp per lane), then
// redistributed across the 4 quads into exact B-operand fragments with
// one permlane32_swap + one permlane16_swap per dword pair:
//   B-frag[bh].reg[jj2] needs j2 = bh*16 + quad*4 + jj2
//     = src dword S[nt = bh*2 + (quad>>1)][rp = jj2&1] @ quad_s = (quad&1)*2 + (jj2>>1)
//   pl32swap(A=S[bh*2][rp], B=S[bh*2+1][rp]) -> A'=[A.lo,B.lo], B'=[A.hi,B.hi]
//   pl16swap(A', B') -> A''=[Aq0,Aq2,Bq0,Bq2]=reg[jj2=rp], B''=[Aq1,Aq3,Bq1,Bq3]=reg[2+rp]
// PV: O^T = mfma(V^T, P^T): out row = quad*4+r = d_local, col = l15 = i.
// Row sums accumulated in f32 on VALU; quad-reduce via shfl_xor in epilogue.
// ---------------------------------------------------------------------------
__global__ __launch_bounds__(256, 4) void attn_kernel(
        const ushort_t* __restrict__ qs,   // [b][c][p], pre-scaled by 0.125
        const ushort_t* __restrict__ ks,   // [b][h][j][d]
        const ushort_t* __restrict__ vt,   // [b][h][d][j]
        ushort_t* __restrict__ ao) {       // [b][i][c]
    const int b = blockIdx.z, h = blockIdx.y;
    const int tid = threadIdx.x, wave = tid >> 6, lane = tid & 63;
    const int l15 = lane & 15, quad = lane >> 4;
    const int iw = blockIdx.x * 128 + wave * 32;

    // Q fragments as MFMA B-operand: B[k=c][n=i]  (same gather as before)
    bf16x8 bq[2][2];
    #pragma unroll
    for (int half = 0; half < 2; ++half)
        #pragma unroll
        for (int kk = 0; kk < 2; ++kk) {
            ushort8 t;
            #pragma unroll
            for (int j = 0; j < 8; ++j) {
                int c = h * HD + kk * 32 + quad * 8 + j;
                int p = iw + half * 16 + l15;
                t[j] = qs[((size_t)b * DIM + c) * HWN + p];
            }
            bq[half][kk] = *(bf16x8*)&t;
        }

    const ushort_t* Kh = &ks[((size_t)b * HEADS + h) * (KVN * HD)];
    const ushort_t* Vh = &vt[((size_t)b * HEADS + h) * (HD * KVN)];

    f32x4 zero = {0.f, 0.f, 0.f, 0.f};
    f32x4 o[2][4] = {{zero, zero, zero, zero}, {zero, zero, zero, zero}};
    float ssum[2] = {0.f, 0.f};

    for (int jt = 0; jt < KVN; jt += 64) {
        // V^T fragments (A-operand of PV): issue early, consume after softmax
        bf16x8 bv[4][2];
        #pragma unroll
        for (int nt = 0; nt < 4; ++nt) {
            const ushort_t* vrow = &Vh[(nt * 16 + l15) * KVN + jt + quad * 8];
            bv[nt][0] = *(const bf16x8*)&vrow[0];
            bv[nt][1] = *(const bf16x8*)&vrow[32];
        }

        // swapped QK^T + exp + pack:  P2[half][nt][rp]
        unsigned P2[2][4][2];
        #pragma unroll
        for (int nt = 0; nt < 4; ++nt) {
            const ushort_t* krow = &Kh[(jt + nt * 16 + l15) * HD + quad * 8];
            bf16x8 bk0 = *(const bf16x8*)&krow[0];
            bf16x8 bk1 = *(const bf16x8*)&krow[32];
            #pragma unroll
            for (int half = 0; half < 2; ++half) {
                f32x4 s = zero;
                s = __builtin_amdgcn_mfma_f32_16x16x32_bf16(bk0, bq[half][0], s, 0, 0, 0);
                s = __builtin_amdgcn_mfma_f32_16x16x32_bf16(bk1, bq[half][1], s, 0, 0, 0);
                float p0 = __builtin_amdgcn_exp2f(s[0] * LOG2E);
                float p1 = __builtin_amdgcn_exp2f(s[1] * LOG2E);
                float p2 = __builtin_amdgcn_exp2f(s[2] * LOG2E);
                float p3 = __builtin_amdgcn_exp2f(s[3] * LOG2E);
                ssum[half] += (p0 + p1) + (p2 + p3);
                P2[half][nt][0] = cvtpk(p0, p1);
                P2[half][nt][1] = cvtpk(p2, p3);
            }
        }

        // cross-lane quad redistribution: P^T dwords -> B-operand fragments
        #pragma unroll
        for (int half = 0; half < 2; ++half)
            #pragma unroll
            for (int bh = 0; bh < 2; ++bh)
                #pragma unroll
                for (int rp = 0; rp < 2; ++rp) {
                    pl32swap(P2[half][bh * 2][rp], P2[half][bh * 2 + 1][rp]);
                    pl16swap(P2[half][bh * 2][rp], P2[half][bh * 2 + 1][rp]);
                }
        bf16x8 bp00 = frag4(P2[0][0][0], P2[0][0][1], P2[0][1][0], P2[0][1][1]);
        bf16x8 bp01 = frag4(P2[0][2][0], P2[0][2][1], P2[0][3][0], P2[0][3][1]);
        bf16x8 bp10 = frag4(P2[1][0][0], P2[1][0][1], P2[1][1][0], P2[1][1][1]);
        bf16x8 bp11 = frag4(P2[1][2][0], P2[1][2][1], P2[1][3][0], P2[1][3][1]);

        // PV:  O^T[d][i] += V^T . P^T
        #pragma unroll
        for (int nt = 0; nt < 4; ++nt) {
            o[0][nt] = __builtin_amdgcn_mfma_f32_16x16x32_bf16(bv[nt][0], bp00, o[0][nt], 0, 0, 0);
            o[0][nt] = __builtin_amdgcn_mfma_f32_16x16x32_bf16(bv[nt][1], bp01, o[0][nt], 0, 0, 0);
            o[1][nt] = __builtin_amdgcn_mfma_f32_16x16x32_bf16(bv[nt][0], bp10, o[1][nt], 0, 0, 0);
            o[1][nt] = __builtin_amdgcn_mfma_f32_16x16x32_bf16(bv[nt][1], bp11, o[1][nt], 0, 0, 0);
        }
    }

    // epilogue: quad-reduce the row sums, scale, packed dwordx2 stores
    #pragma unroll
    for (int half = 0; half < 2; ++half) {
        float t = ssum[half];
        t += __shfl_xor(t, 16);
        t += __shfl_xor(t, 32);
        float invl = 1.0f / t;
        int i = iw + half * 16 + l15;
        ushort_t* dst = &ao[((size_t)b * HWN + i) * DIM + h * HD];
        #pragma unroll
        for (int nt = 0; nt < 4; ++nt) {
            unsigned d0 = cvtpk(o[half][nt][0] * invl, o[half][nt][1] * invl);
            unsigned d1 = cvtpk(o[half][nt][2] * invl, o[half][nt][3] * invl);
            uint2v w; w[0] = d0; w[1] = d1;
            *(uint2v*)&dst[nt * 16 + quad * 4] = w;
        }
    }
}

// ---------------------------------------------------------------------------
// Kernel 4: output projection.  out[b][o][p] = sum_c Wout[o][c] * AO[b][p][c]
// ---------------------------------------------------------------------------
__global__ __launch_bounds__(256) void outproj_kernel(
        const ushort_t* __restrict__ ao, const ushort_t* __restrict__ woutb,
        float* __restrict__ out) {
    const int b  = blockIdx.z;
    const int m0 = blockIdx.y * 64;
    const int p0 = blockIdx.x * 64;

    __shared__ ushort_t ldsA[64 * 40];
    __shared__ ushort_t ldsB[64 * 40];

    const int tid  = threadIdx.x;
    const int wave = tid >> 6;
    const int lane = tid & 63;
    const int l15  = lane & 15;
    const int quad = lane >> 4;
    const int mw   = (wave >> 1) * 32;
    const int nw   = (wave & 1) * 32;

    f32x4 zero = {0.f, 0.f, 0.f, 0.f};
    f32x4 acc[2][2] = {{zero, zero}, {zero, zero}};

    for (int k0 = 0; k0 < DIM; k0 += 32) {
        int row = tid >> 2, ko = (tid & 3) * 8;
        *(ushort8*)&ldsA[row * 40 + ko] =
            *(const ushort8*)&woutb[(m0 + row) * DIM + k0 + ko];
        *(ushort8*)&ldsB[row * 40 + ko] =
            *(const ushort8*)&ao[((size_t)b * HWN + p0 + row) * DIM + k0 + ko];
        __syncthreads();
        bf16x8 a0 = *(const bf16x8*)&ldsA[(mw + l15) * 40 + quad * 8];
        bf16x8 a1 = *(const bf16x8*)&ldsA[(mw + 16 + l15) * 40 + quad * 8];
        bf16x8 b0 = *(const bf16x8*)&ldsB[(nw + l15) * 40 + quad * 8];
        bf16x8 b1 = *(const bf16x8*)&ldsB[(nw + 16 + l15) * 40 + quad * 8];
        acc[0][0] = __builtin_amdgcn_mfma_f32_16x16x32_bf16(a0, b0, acc[0][0], 0, 0, 0);
        acc[0][1] = __builtin_amdgcn_mfma_f32_16x16x32_bf16(a0, b1, acc[0][1], 0, 0, 0);
        acc[1][0] = __builtin_amdgcn_mfma_f32_16x16x32_bf16(a1, b0, acc[1][0], 0, 0, 0);
        acc[1][1] = __builtin_amdgcn_mfma_f32_16x16x32_bf16(a1, b1, acc[1][1], 0, 0, 0);
        __syncthreads();
    }

    #pragma unroll
    for (int mi = 0; mi < 2; ++mi)
        #pragma unroll
        for (int ni = 0; ni < 2; ++ni)
            #pragma unroll
            for (int r = 0; r < 4; ++r) {
                int m = m0 + mw + mi * 16 + quad * 4 + r;
                int n = p0 + nw + ni * 16 + l15;
                out[((size_t)b * DIM + m) * HWN + n] = acc[mi][ni][r];
            }
}

// ---------------------------------------------------------------------------
extern "C" void kernel_launch(void* const* d_in, const int* in_sizes, int n_in,
                              void* d_out, int out_size, void* d_ws, size_t ws_size,
                              hipStream_t stream) {
    const float* x    = (const float*)d_in[0];  // [4][512][64][64] f32
    const float* wq   = (const float*)d_in[1];  // [512][512] f32
    const float* wkv  = (const float*)d_in[2];  // [1024][512][2][2] f32
    const float* wout = (const float*)d_in[3];  // [512][512] f32
    float* out = (float*)d_out;                 // [4][512][64][64] f32

    char* ws = (char*)d_ws;
    ushort_t* xT    = (ushort_t*)(ws);               // 16.78 MB  [b][p][c]
    ushort_t* qsb   = (ushort_t*)(ws + 16777216);    // 16.78 MB  [b][c][p]
    ushort_t* ksb   = (ushort_t*)(ws + 33554432);    //  4.19 MB  [b][h][j][d]
    ushort_t* vtb   = (ushort_t*)(ws + 37748736);    //  4.19 MB  [b][h][d][j]
    ushort_t* aob   = (ushort_t*)(ws + 41943040);    // 16.78 MB  [b][i][c]
    ushort_t* wqb   = (ushort_t*)(ws + 58720256);    //  0.52 MB
    ushort_t* wkvT  = (ushort_t*)(ws + 59244544);    //  4.19 MB  [o2][(q,c)]
    ushort_t* woutb = (ushort_t*)(ws + 63438848);    //  0.52 MB

    cvt_xT_kernel  <<<dim3(64, 8, 4), 256, 0, stream>>>(x, xT);
    cvt_kernel     <<<dim3(128),      256, 0, stream>>>(wq, wqb, 32768);
    cvt_wkvT_kernel<<<dim3(2048),     256, 0, stream>>>(wkv, wkvT);
    cvt_kernel     <<<dim3(128),      256, 0, stream>>>(wout, woutb, 32768);

    qproj_kernel  <<<dim3(64, 8, 4),  256, 0, stream>>>(xT, wqb, qsb);
    kv_kernel     <<<dim3(16, 16, 4), 256, 0, stream>>>(xT, wkvT, ksb, vtb);
    attn_kernel   <<<dim3(32, 8, 4),  256, 0, stream>>>(qsb, ksb, vtb, aob);
    outproj_kernel<<<dim3(64, 8, 4),  256, 0, stream>>>(aob, woutb, out);
}

// Round 2
// 231.242 us; speedup vs baseline: 1.3206x; 1.3206x over previous
//
#include <hip/hip_runtime.h>
#include <hip/hip_bf16.h>

typedef __bf16 bf16x8 __attribute__((ext_vector_type(8)));
typedef float f32x4 __attribute__((ext_vector_type(4)));
typedef unsigned short ushort_t;
typedef ushort_t ushort8 __attribute__((ext_vector_type(8)));
typedef unsigned uint2v __attribute__((ext_vector_type(2)));
typedef unsigned uint4v __attribute__((ext_vector_type(4)));

#define DIM 512
#define HEADS 8
#define HD 64
#define HWN 4096   // 64*64 queries per batch
#define KVN 1024   // 32*32 kv tokens per batch
#define KKV 2048   // 512*2*2 im2col K for the strided conv
#define LOG2E 1.44269504f

__device__ __forceinline__ ushort_t f2bf(float f) {
    union { float f; unsigned u; } v; v.f = f;
    unsigned r = v.u + 0x7fffu + ((v.u >> 16) & 1u);
    return (ushort_t)(r >> 16);
}

// pack two f32 -> one dword of 2 bf16 (RNE), low16 = lo
__device__ __forceinline__ unsigned cvtpk(float lo, float hi) {
    unsigned r;
    asm("v_cvt_pk_bf16_f32 %0, %1, %2" : "=v"(r) : "v"(lo), "v"(hi));
    return r;
}

// v_permlane32_swap_b32: a' = [a.lo32, b.lo32], b' = [a.hi32, b.hi32]
__device__ __forceinline__ void pl32swap(unsigned &a, unsigned &b) {
    asm("v_permlane32_swap_b32 %0, %1" : "+v"(a), "+v"(b));
}
// v_permlane16_swap_b32
__device__ __forceinline__ void pl16swap(unsigned &a, unsigned &b) {
    asm("v_permlane16_swap_b32 %0, %1" : "+v"(a), "+v"(b));
}

__device__ __forceinline__ bf16x8 frag4(unsigned a, unsigned b, unsigned c, unsigned d) {
    uint4v t; t[0] = a; t[1] = b; t[2] = c; t[3] = d;
    return __builtin_bit_cast(bf16x8, t);
}

// async global->LDS, 16 B per lane; lds dest is wave-uniform base + lane*16
__device__ __forceinline__ void gload_lds16(const ushort_t* g, ushort_t* l) {
    __builtin_amdgcn_global_load_lds(
        (const __attribute__((address_space(1))) unsigned int*)(const void*)g,
        (__attribute__((address_space(3))) unsigned int*)(void*)l,
        16, 0, 0);
}

// ---------------------------------------------------------------------------
// Kernel 0a: small f32 -> bf16 convert (wq, wout)
// ---------------------------------------------------------------------------
__global__ __launch_bounds__(256) void cvt_kernel(
        const float* __restrict__ src, ushort_t* __restrict__ dst, int n8) {
    int i = blockIdx.x * 256 + threadIdx.x;
    if (i >= n8) return;
    const float* p = &src[(size_t)i * 8];
    f32x4 v0 = *(const f32x4*)&p[0];
    f32x4 v1 = *(const f32x4*)&p[4];
    ushort8 w;
    w[0] = f2bf(v0[0]); w[1] = f2bf(v0[1]); w[2] = f2bf(v0[2]); w[3] = f2bf(v0[3]);
    w[4] = f2bf(v1[0]); w[5] = f2bf(v1[1]); w[6] = f2bf(v1[2]); w[7] = f2bf(v1[3]);
    *(ushort8*)&dst[i * 8] = w;
}

// ---------------------------------------------------------------------------
// Kernel 0b: x f32 [b][c][p] -> xT bf16 [b][p][c]   (tiled 64x64 transpose)
// ---------------------------------------------------------------------------
__global__ __launch_bounds__(256) void cvt_xT_kernel(
        const float* __restrict__ x, ushort_t* __restrict__ xT) {
    const int b  = blockIdx.z;
    const int c0 = blockIdx.y * 64;
    const int p0 = blockIdx.x * 64;
    __shared__ ushort_t tile[64 * 72];

    const int tid = threadIdx.x;
    {   // load + convert: each thread 16 floats of one c-row
        int r = tid >> 2, pc = (tid & 3) * 16;
        const float* src = &x[((size_t)b * DIM + c0 + r) * HWN + p0 + pc];
        f32x4 v0 = *(const f32x4*)&src[0];
        f32x4 v1 = *(const f32x4*)&src[4];
        f32x4 v2 = *(const f32x4*)&src[8];
        f32x4 v3 = *(const f32x4*)&src[12];
        ushort8 w0, w1;
        w0[0]=f2bf(v0[0]); w0[1]=f2bf(v0[1]); w0[2]=f2bf(v0[2]); w0[3]=f2bf(v0[3]);
        w0[4]=f2bf(v1[0]); w0[5]=f2bf(v1[1]); w0[6]=f2bf(v1[2]); w0[7]=f2bf(v1[3]);
        w1[0]=f2bf(v2[0]); w1[1]=f2bf(v2[1]); w1[2]=f2bf(v2[2]); w1[3]=f2bf(v2[3]);
        w1[4]=f2bf(v3[0]); w1[5]=f2bf(v3[1]); w1[6]=f2bf(v3[2]); w1[7]=f2bf(v3[3]);
        *(ushort8*)&tile[r * 72 + pc]     = w0;
        *(ushort8*)&tile[r * 72 + pc + 8] = w1;
    }
    __syncthreads();
    {   // write transposed: each thread 16 c-values of one p-row
        int p = tid >> 2, cc = (tid & 3) * 16;
        ushort8 w0, w1;
        #pragma unroll
        for (int j = 0; j < 8; ++j) {
            w0[j] = tile[(cc + j) * 72 + p];
            w1[j] = tile[(cc + 8 + j) * 72 + p];
        }
        ushort_t* dst = &xT[((size_t)b * HWN + p0 + p) * DIM + c0 + cc];
        *(ushort8*)&dst[0] = w0;
        *(ushort8*)&dst[8] = w1;
    }
}

// ---------------------------------------------------------------------------
// Kernel 0c: wkv f32 [o2][c][di][dj] -> wkvT bf16 [o2][(di*2+dj)*512 + c]
// ---------------------------------------------------------------------------
__global__ __launch_bounds__(256) void cvt_wkvT_kernel(
        const float* __restrict__ wkv, ushort_t* __restrict__ wkvT) {
    int i = blockIdx.x * 256 + threadIdx.x;     // (o2, c) pair
    if (i >= 1024 * 512) return;
    int o2 = i >> 9, c = i & 511;
    f32x4 v = *(const f32x4*)&wkv[(size_t)i * 4];  // the 4 q values for this (o2,c)
    #pragma unroll
    for (int q = 0; q < 4; ++q)
        wkvT[(size_t)o2 * KKV + q * 512 + c] = f2bf(v[q]);
}

// ---------------------------------------------------------------------------
// Kernel 1: Q projection.  Qs[b][o][p] = (0.125*log2e) * sum_c Wq[o][c] * X[c][p]
// Pre-scaled by log2(e) so attention uses exp2 directly.
// ---------------------------------------------------------------------------
__global__ __launch_bounds__(256) void qproj_kernel(
        const ushort_t* __restrict__ xT, const ushort_t* __restrict__ wqb,
        ushort_t* __restrict__ qs) {
    const int b  = blockIdx.z;
    const int m0 = blockIdx.y * 64;
    const int p0 = blockIdx.x * 64;

    __shared__ ushort_t ldsA[64 * 40];
    __shared__ ushort_t ldsB[64 * 40];

    const int tid  = threadIdx.x;
    const int wave = tid >> 6;
    const int lane = tid & 63;
    const int l15  = lane & 15;
    const int quad = lane >> 4;
    const int mw   = (wave >> 1) * 32;
    const int nw   = (wave & 1) * 32;

    f32x4 zero = {0.f, 0.f, 0.f, 0.f};
    f32x4 acc[2][2] = {{zero, zero}, {zero, zero}};

    for (int k0 = 0; k0 < DIM; k0 += 32) {
        int row = tid >> 2, ko = (tid & 3) * 8;
        *(ushort8*)&ldsA[row * 40 + ko] =
            *(const ushort8*)&wqb[(m0 + row) * DIM + k0 + ko];
        *(ushort8*)&ldsB[row * 40 + ko] =
            *(const ushort8*)&xT[((size_t)b * HWN + p0 + row) * DIM + k0 + ko];
        __syncthreads();
        bf16x8 a0 = *(const bf16x8*)&ldsA[(mw + l15) * 40 + quad * 8];
        bf16x8 a1 = *(const bf16x8*)&ldsA[(mw + 16 + l15) * 40 + quad * 8];
        bf16x8 b0 = *(const bf16x8*)&ldsB[(nw + l15) * 40 + quad * 8];
        bf16x8 b1 = *(const bf16x8*)&ldsB[(nw + 16 + l15) * 40 + quad * 8];
        acc[0][0] = __builtin_amdgcn_mfma_f32_16x16x32_bf16(a0, b0, acc[0][0], 0, 0, 0);
        acc[0][1] = __builtin_amdgcn_mfma_f32_16x16x32_bf16(a0, b1, acc[0][1], 0, 0, 0);
        acc[1][0] = __builtin_amdgcn_mfma_f32_16x16x32_bf16(a1, b0, acc[1][0], 0, 0, 0);
        acc[1][1] = __builtin_amdgcn_mfma_f32_16x16x32_bf16(a1, b1, acc[1][1], 0, 0, 0);
        __syncthreads();
    }

    #pragma unroll
    for (int mi = 0; mi < 2; ++mi)
        #pragma unroll
        for (int ni = 0; ni < 2; ++ni)
            #pragma unroll
            for (int r = 0; r < 4; ++r) {
                int m = m0 + mw + mi * 16 + quad * 4 + r;
                int n = p0 + nw + ni * 16 + l15;
                qs[((size_t)b * DIM + m) * HWN + n] =
                    f2bf(acc[mi][ni][r] * (0.125f * LOG2E));
            }
}

// ---------------------------------------------------------------------------
// Kernel 2: KV conv-GEMM with k' = (q=di*2+dj, c) ordering.
// ---------------------------------------------------------------------------
__global__ __launch_bounds__(256) void kv_kernel(
        const ushort_t* __restrict__ xT, const ushort_t* __restrict__ wkvT,
        ushort_t* __restrict__ ks, ushort_t* __restrict__ vt) {
    const int b  = blockIdx.z;
    const int m0 = blockIdx.y * 64;
    const int j0 = blockIdx.x * 64;

    __shared__ ushort_t ldsA[64 * 40];
    __shared__ ushort_t ldsB[64 * 40];
    __shared__ ushort_t cbuf[64 * 72];

    const int tid  = threadIdx.x;
    const int wave = tid >> 6;
    const int lane = tid & 63;
    const int l15  = lane & 15;
    const int quad = lane >> 4;
    const int mw   = (wave >> 1) * 32;
    const int nw   = (wave & 1) * 32;

    f32x4 zero = {0.f, 0.f, 0.f, 0.f};
    f32x4 acc[2][2] = {{zero, zero}, {zero, zero}};

    const int row = tid >> 2, ko = (tid & 3) * 8;
    const int yj = (j0 + row) >> 5, xj = (j0 + row) & 31;

    for (int k0 = 0; k0 < KKV; k0 += 32) {
        int q  = k0 >> 9;                  // (di,dj) block
        int c0 = k0 & 511;
        int di = q >> 1, dj = q & 1;
        int p  = (2 * yj + di) * 64 + 2 * xj + dj;
        *(ushort8*)&ldsA[row * 40 + ko] =
            *(const ushort8*)&wkvT[(size_t)(m0 + row) * KKV + k0 + ko];
        *(ushort8*)&ldsB[row * 40 + ko] =
            *(const ushort8*)&xT[((size_t)b * HWN + p) * DIM + c0 + ko];
        __syncthreads();
        bf16x8 a0 = *(const bf16x8*)&ldsA[(mw + l15) * 40 + quad * 8];
        bf16x8 a1 = *(const bf16x8*)&ldsA[(mw + 16 + l15) * 40 + quad * 8];
        bf16x8 b0 = *(const bf16x8*)&ldsB[(nw + l15) * 40 + quad * 8];
        bf16x8 b1 = *(const bf16x8*)&ldsB[(nw + 16 + l15) * 40 + quad * 8];
        acc[0][0] = __builtin_amdgcn_mfma_f32_16x16x32_bf16(a0, b0, acc[0][0], 0, 0, 0);
        acc[0][1] = __builtin_amdgcn_mfma_f32_16x16x32_bf16(a0, b1, acc[0][1], 0, 0, 0);
        acc[1][0] = __builtin_amdgcn_mfma_f32_16x16x32_bf16(a1, b0, acc[1][0], 0, 0, 0);
        acc[1][1] = __builtin_amdgcn_mfma_f32_16x16x32_bf16(a1, b1, acc[1][1], 0, 0, 0);
        __syncthreads();
    }

    if (m0 < DIM) {
        int h = m0 >> 6;
        #pragma unroll
        for (int mi = 0; mi < 2; ++mi)
            #pragma unroll
            for (int ni = 0; ni < 2; ++ni)
                #pragma unroll
                for (int r = 0; r < 4; ++r) {
                    int m = mw + mi * 16 + quad * 4 + r;
                    int n = nw + ni * 16 + l15;
                    cbuf[n * 72 + m] = f2bf(acc[mi][ni][r]);
                }
        __syncthreads();
        int n = tid >> 2, mo = (tid & 3) * 16;
        ushort8 v0 = *(const ushort8*)&cbuf[n * 72 + mo];
        ushort8 v1 = *(const ushort8*)&cbuf[n * 72 + mo + 8];
        ushort_t* dst = &ks[(((size_t)b * HEADS + h) * KVN + j0 + n) * HD + mo];
        *(ushort8*)&dst[0] = v0;
        *(ushort8*)&dst[8] = v1;
    } else {
        int h = (m0 - DIM) >> 6;
        #pragma unroll
        for (int mi = 0; mi < 2; ++mi)
            #pragma unroll
            for (int ni = 0; ni < 2; ++ni)
                #pragma unroll
                for (int r = 0; r < 4; ++r) {
                    int dd = mw + mi * 16 + quad * 4 + r;
                    int n  = nw + ni * 16 + l15;
                    vt[(((size_t)b * HEADS + h) * HD + dd) * KVN + j0 + n] =
                        f2bf(acc[mi][ni][r]);
                }
    }
}

// ---------------------------------------------------------------------------
// Kernel 3: attention — LDS-staged K/V (double-buffered, shared by 4 waves),
// 64 queries/wave, in-register softmax (swapped QK^T + cvt_pk + permlane).
//
// K/V tiles are [64 rows][128 B] in LDS. To kill the 128B-row bank pathology:
// linear global_load_lds dest + INVERSE-swizzled per-lane global source +
// XOR-swizzled ds_read (rule #21): LDS[row][c16] holds global chunk c16^(row&7).
// ---------------------------------------------------------------------------
__global__ __launch_bounds__(256, 2) void attn_kernel(
        const ushort_t* __restrict__ qs,   // [b][c][p], pre-scaled by 0.125*log2e
        const ushort_t* __restrict__ ks,   // [b][h][j][d]
        const ushort_t* __restrict__ vt,   // [b][h][d][j]
        ushort_t* __restrict__ ao) {       // [b][i][c]
    const int b = blockIdx.z, h = blockIdx.y;
    const int tid = threadIdx.x, wave = tid >> 6, lane = tid & 63;
    const int l15 = lane & 15, quad = lane >> 4;
    const int s7  = l15 & 7;
    const int iw = blockIdx.x * 256 + wave * 64;

    __shared__ ushort_t ldsK[2][64 * 64];
    __shared__ ushort_t ldsV[2][64 * 64];

    const ushort_t* Kh = &ks[((size_t)b * HEADS + h) * (KVN * HD)];
    const ushort_t* Vh = &vt[((size_t)b * HEADS + h) * (HD * KVN)];

    // staging geometry: lane covers LDS row srow(+32), 16B-chunk (lane&7);
    // source chunk is XOR'd so the ds_read-side swizzle sees linear data.
    const int srow = wave * 8 + (lane >> 3);
    const int schk = (lane & 7) ^ (lane >> 3);
    const ushort_t* kp0 = Kh + srow * HD + schk * 8;
    const ushort_t* kp1 = Kh + (srow + 32) * HD + schk * 8;
    const ushort_t* vp0 = Vh + (size_t)srow * KVN + schk * 8;
    const ushort_t* vp1 = Vh + (size_t)(srow + 32) * KVN + schk * 8;

    // Q fragments as MFMA B-operand, 4 i-tiles of 16
    bf16x8 bq[4][2];
    #pragma unroll
    for (int ih = 0; ih < 4; ++ih)
        #pragma unroll
        for (int kk = 0; kk < 2; ++kk) {
            ushort8 t;
            #pragma unroll
            for (int j = 0; j < 8; ++j) {
                int c = h * HD + kk * 32 + quad * 8 + j;
                int p = iw + ih * 16 + l15;
                t[j] = qs[((size_t)b * DIM + c) * HWN + p];
            }
            bq[ih][kk] = *(bf16x8*)&t;
        }

    f32x4 zero = {0.f, 0.f, 0.f, 0.f};
    f32x4 o[4][4];
    #pragma unroll
    for (int ih = 0; ih < 4; ++ih)
        #pragma unroll
        for (int nt = 0; nt < 4; ++nt) o[ih][nt] = zero;
    float ssum[4] = {0.f, 0.f, 0.f, 0.f};

    // prologue: stage chunk 0 into buf 0
    gload_lds16(kp0, &ldsK[0][wave * 512]);
    gload_lds16(kp1, &ldsK[0][wave * 512 + 2048]);
    gload_lds16(vp0, &ldsV[0][wave * 512]);
    gload_lds16(vp1, &ldsV[0][wave * 512 + 2048]);
    asm volatile("s_waitcnt vmcnt(0)" ::: "memory");
    __syncthreads();

    for (int t = 0; t < 16; ++t) {
        const int cur = t & 1;
        if (t < 15) {   // prefetch next chunk into the other buffer
            const int jn = (t + 1) * 64;
            gload_lds16(kp0 + jn * HD, &ldsK[cur ^ 1][wave * 512]);
            gload_lds16(kp1 + jn * HD, &ldsK[cur ^ 1][wave * 512 + 2048]);
            gload_lds16(vp0 + jn,      &ldsV[cur ^ 1][wave * 512]);
            gload_lds16(vp1 + jn,      &ldsV[cur ^ 1][wave * 512 + 2048]);
        }

        // swapped QK^T + exp2 + pack
        unsigned P2[4][4][2];
        #pragma unroll
        for (int nt = 0; nt < 4; ++nt) {
            const ushort_t* kb = &ldsK[cur][(nt * 16 + l15) * 64];
            bf16x8 bk0 = *(const bf16x8*)&kb[(quad ^ s7) * 8];
            bf16x8 bk1 = *(const bf16x8*)&kb[((quad + 4) ^ s7) * 8];
            #pragma unroll
            for (int ih = 0; ih < 4; ++ih) {
                f32x4 s = zero;
                s = __builtin_amdgcn_mfma_f32_16x16x32_bf16(bk0, bq[ih][0], s, 0, 0, 0);
                s = __builtin_amdgcn_mfma_f32_16x16x32_bf16(bk1, bq[ih][1], s, 0, 0, 0);
                float p0 = __builtin_amdgcn_exp2f(s[0]);
                float p1 = __builtin_amdgcn_exp2f(s[1]);
                float p2 = __builtin_amdgcn_exp2f(s[2]);
                float p3 = __builtin_amdgcn_exp2f(s[3]);
                ssum[ih] += (p0 + p1) + (p2 + p3);
                P2[ih][nt][0] = cvtpk(p0, p1);
                P2[ih][nt][1] = cvtpk(p2, p3);
            }
        }

        // cross-lane quad redistribution: P^T dwords -> B-operand fragments
        #pragma unroll
        for (int ih = 0; ih < 4; ++ih)
            #pragma unroll
            for (int bh = 0; bh < 2; ++bh)
                #pragma unroll
                for (int rp = 0; rp < 2; ++rp) {
                    pl32swap(P2[ih][bh * 2][rp], P2[ih][bh * 2 + 1][rp]);
                    pl16swap(P2[ih][bh * 2][rp], P2[ih][bh * 2 + 1][rp]);
                }
        bf16x8 bp[4][2];
        #pragma unroll
        for (int ih = 0; ih < 4; ++ih) {
            bp[ih][0] = frag4(P2[ih][0][0], P2[ih][0][1], P2[ih][1][0], P2[ih][1][1]);
            bp[ih][1] = frag4(P2[ih][2][0], P2[ih][2][1], P2[ih][3][0], P2[ih][3][1]);
        }

        // PV:  O^T[d][i] += V^T . P^T
        #pragma unroll
        for (int nt = 0; nt < 4; ++nt) {
            const ushort_t* vb = &ldsV[cur][(nt * 16 + l15) * 64];
            bf16x8 bv0 = *(const bf16x8*)&vb[(quad ^ s7) * 8];
            bf16x8 bv1 = *(const bf16x8*)&vb[((quad + 4) ^ s7) * 8];
            #pragma unroll
            for (int ih = 0; ih < 4; ++ih) {
                o[ih][nt] = __builtin_amdgcn_mfma_f32_16x16x32_bf16(bv0, bp[ih][0], o[ih][nt], 0, 0, 0);
                o[ih][nt] = __builtin_amdgcn_mfma_f32_16x16x32_bf16(bv1, bp[ih][1], o[ih][nt], 0, 0, 0);
            }
        }

        asm volatile("s_waitcnt vmcnt(0)" ::: "memory");
        __syncthreads();
    }

    // epilogue: quad-reduce the row sums, scale, packed dwordx2 stores
    #pragma unroll
    for (int ih = 0; ih < 4; ++ih) {
        float tsum = ssum[ih];
        tsum += __shfl_xor(tsum, 16);
        tsum += __shfl_xor(tsum, 32);
        float invl = 1.0f / tsum;
        int i = iw + ih * 16 + l15;
        ushort_t* dst = &ao[((size_t)b * HWN + i) * DIM + h * HD];
        #pragma unroll
        for (int nt = 0; nt < 4; ++nt) {
            unsigned d0 = cvtpk(o[ih][nt][0] * invl, o[ih][nt][1] * invl);
            unsigned d1 = cvtpk(o[ih][nt][2] * invl, o[ih][nt][3] * invl);
            uint2v w; w[0] = d0; w[1] = d1;
            *(uint2v*)&dst[nt * 16 + quad * 4] = w;
        }
    }
}

// ---------------------------------------------------------------------------
// Kernel 4: output projection.  out[b][o][p] = sum_c Wout[o][c] * AO[b][p][c]
// ---------------------------------------------------------------------------
__global__ __launch_bounds__(256) void outproj_kernel(
        const ushort_t* __restrict__ ao, const ushort_t* __restrict__ woutb,
        float* __restrict__ out) {
    const int b  = blockIdx.z;
    const int m0 = blockIdx.y * 64;
    const int p0 = blockIdx.x * 64;

    __shared__ ushort_t ldsA[64 * 40];
    __shared__ ushort_t ldsB[64 * 40];

    const int tid  = threadIdx.x;
    const int wave = tid >> 6;
    const int lane = tid & 63;
    const int l15  = lane & 15;
    const int quad = lane >> 4;
    const int mw   = (wave >> 1) * 32;
    const int nw   = (wave & 1) * 32;

    f32x4 zero = {0.f, 0.f, 0.f, 0.f};
    f32x4 acc[2][2] = {{zero, zero}, {zero, zero}};

    for (int k0 = 0; k0 < DIM; k0 += 32) {
        int row = tid >> 2, ko = (tid & 3) * 8;
        *(ushort8*)&ldsA[row * 40 + ko] =
            *(const ushort8*)&woutb[(m0 + row) * DIM + k0 + ko];
        *(ushort8*)&ldsB[row * 40 + ko] =
            *(const ushort8*)&ao[((size_t)b * HWN + p0 + row) * DIM + k0 + ko];
        __syncthreads();
        bf16x8 a0 = *(const bf16x8*)&ldsA[(mw + l15) * 40 + quad * 8];
        bf16x8 a1 = *(const bf16x8*)&ldsA[(mw + 16 + l15) * 40 + quad * 8];
        bf16x8 b0 = *(const bf16x8*)&ldsB[(nw + l15) * 40 + quad * 8];
        bf16x8 b1 = *(const bf16x8*)&ldsB[(nw + 16 + l15) * 40 + quad * 8];
        acc[0][0] = __builtin_amdgcn_mfma_f32_16x16x32_bf16(a0, b0, acc[0][0], 0, 0, 0);
        acc[0][1] = __builtin_amdgcn_mfma_f32_16x16x32_bf16(a0, b1, acc[0][1], 0, 0, 0);
        acc[1][0] = __builtin_amdgcn_mfma_f32_16x16x32_bf16(a1, b0, acc[1][0], 0, 0, 0);
        acc[1][1] = __builtin_amdgcn_mfma_f32_16x16x32_bf16(a1, b1, acc[1][1], 0, 0, 0);
        __syncthreads();
    }

    #pragma unroll
    for (int mi = 0; mi < 2; ++mi)
        #pragma unroll
        for (int ni = 0; ni < 2; ++ni)
            #pragma unroll
            for (int r = 0; r < 4; ++r) {
                int m = m0 + mw + mi * 16 + quad * 4 + r;
                int n = p0 + nw + ni * 16 + l15;
                out[((size_t)b * DIM + m) * HWN + n] = acc[mi][ni][r];
            }
}

// ---------------------------------------------------------------------------
extern "C" void kernel_launch(void* const* d_in, const int* in_sizes, int n_in,
                              void* d_out, int out_size, void* d_ws, size_t ws_size,
                              hipStream_t stream) {
    const float* x    = (const float*)d_in[0];  // [4][512][64][64] f32
    const float* wq   = (const float*)d_in[1];  // [512][512] f32
    const float* wkv  = (const float*)d_in[2];  // [1024][512][2][2] f32
    const float* wout = (const float*)d_in[3];  // [512][512] f32
    float* out = (float*)d_out;                 // [4][512][64][64] f32

    char* ws = (char*)d_ws;
    ushort_t* xT    = (ushort_t*)(ws);               // 16.78 MB  [b][p][c]
    ushort_t* qsb   = (ushort_t*)(ws + 16777216);    // 16.78 MB  [b][c][p]
    ushort_t* ksb   = (ushort_t*)(ws + 33554432);    //  4.19 MB  [b][h][j][d]
    ushort_t* vtb   = (ushort_t*)(ws + 37748736);    //  4.19 MB  [b][h][d][j]
    ushort_t* aob   = (ushort_t*)(ws + 41943040);    // 16.78 MB  [b][i][c]
    ushort_t* wqb   = (ushort_t*)(ws + 58720256);    //  0.52 MB
    ushort_t* wkvT  = (ushort_t*)(ws + 59244544);    //  4.19 MB  [o2][(q,c)]
    ushort_t* woutb = (ushort_t*)(ws + 63438848);    //  0.52 MB

    cvt_xT_kernel  <<<dim3(64, 8, 4), 256, 0, stream>>>(x, xT);
    cvt_kernel     <<<dim3(128),      256, 0, stream>>>(wq, wqb, 32768);
    cvt_wkvT_kernel<<<dim3(2048),     256, 0, stream>>>(wkv, wkvT);
    cvt_kernel     <<<dim3(128),      256, 0, stream>>>(wout, woutb, 32768);

    qproj_kernel  <<<dim3(64, 8, 4),  256, 0, stream>>>(xT, wqb, qsb);
    kv_kernel     <<<dim3(16, 16, 4), 256, 0, stream>>>(xT, wkvT, ksb, vtb);
    attn_kernel   <<<dim3(16, 8, 4),  256, 0, stream>>>(qsb, ksb, vtb, aob);
    outproj_kernel<<<dim3(64, 8, 4),  256, 0, stream>>>(aob, woutb, out);
}

// Round 3
// 217.978 us; speedup vs baseline: 1.4009x; 1.0608x over previous
//
#include <hip/hip_runtime.h>
#include <hip/hip_bf16.h>

typedef __bf16 bf16x8 __attribute__((ext_vector_type(8)));
typedef float f32x4 __attribute__((ext_vector_type(4)));
typedef unsigned short ushort_t;
typedef ushort_t ushort8 __attribute__((ext_vector_type(8)));
typedef unsigned uint2v __attribute__((ext_vector_type(2)));
typedef unsigned uint4v __attribute__((ext_vector_type(4)));

#define DIM 512
#define HEADS 8
#define HD 64
#define HWN 4096   // 64*64 queries per batch
#define KVN 1024   // 32*32 kv tokens per batch
#define KKV 2048   // 512*2*2 im2col K for the strided conv
#define LOG2E 1.44269504f

__device__ __forceinline__ ushort_t f2bf(float f) {
    union { float f; unsigned u; } v; v.f = f;
    unsigned r = v.u + 0x7fffu + ((v.u >> 16) & 1u);
    return (ushort_t)(r >> 16);
}

// pack two f32 -> one dword of 2 bf16 (RNE), low16 = lo
__device__ __forceinline__ unsigned cvtpk(float lo, float hi) {
    unsigned r;
    asm("v_cvt_pk_bf16_f32 %0, %1, %2" : "=v"(r) : "v"(lo), "v"(hi));
    return r;
}

// v_permlane32_swap_b32: a' = [a.lo32, b.lo32], b' = [a.hi32, b.hi32]
__device__ __forceinline__ void pl32swap(unsigned &a, unsigned &b) {
    asm("v_permlane32_swap_b32 %0, %1" : "+v"(a), "+v"(b));
}
// v_permlane16_swap_b32
__device__ __forceinline__ void pl16swap(unsigned &a, unsigned &b) {
    asm("v_permlane16_swap_b32 %0, %1" : "+v"(a), "+v"(b));
}

__device__ __forceinline__ bf16x8 frag4(unsigned a, unsigned b, unsigned c, unsigned d) {
    uint4v t; t[0] = a; t[1] = b; t[2] = c; t[3] = d;
    return __builtin_bit_cast(bf16x8, t);
}

// async global->LDS, 16 B per lane; lds dest is wave-uniform base + lane*16
__device__ __forceinline__ void gload_lds16(const ushort_t* g, ushort_t* l) {
    __builtin_amdgcn_global_load_lds(
        (const __attribute__((address_space(1))) unsigned int*)(const void*)g,
        (__attribute__((address_space(3))) unsigned int*)(void*)l,
        16, 0, 0);
}

// m97-style per-wave K-step: 4 A-frags, 4 B-frags, 16 MFMA.  LDS tiles are
// linear [128 rows][32 k-elems] (64 B rows).
__device__ __forceinline__ void kstep_mfma(
        const ushort_t* __restrict__ ldsA, const ushort_t* __restrict__ ldsB,
        int wm, int wn, int l15, int quad, f32x4 (&acc)[4][4]) {
    bf16x8 a[4], bb[4];
    #pragma unroll
    for (int i = 0; i < 4; ++i)
        a[i] = *(const bf16x8*)&ldsA[(wm + i * 16 + l15) * 32 + quad * 8];
    #pragma unroll
    for (int j = 0; j < 4; ++j)
        bb[j] = *(const bf16x8*)&ldsB[(wn + j * 16 + l15) * 32 + quad * 8];
    #pragma unroll
    for (int i = 0; i < 4; ++i)
        #pragma unroll
        for (int j = 0; j < 4; ++j)
            acc[i][j] = __builtin_amdgcn_mfma_f32_16x16x32_bf16(a[i], bb[j], acc[i][j], 0, 0, 0);
}

// ---------------------------------------------------------------------------
// Kernel 0a: small f32 -> bf16 convert (wq, wout)
// ---------------------------------------------------------------------------
__global__ __launch_bounds__(256) void cvt_kernel(
        const float* __restrict__ src, ushort_t* __restrict__ dst, int n8) {
    int i = blockIdx.x * 256 + threadIdx.x;
    if (i >= n8) return;
    const float* p = &src[(size_t)i * 8];
    f32x4 v0 = *(const f32x4*)&p[0];
    f32x4 v1 = *(const f32x4*)&p[4];
    ushort8 w;
    w[0] = f2bf(v0[0]); w[1] = f2bf(v0[1]); w[2] = f2bf(v0[2]); w[3] = f2bf(v0[3]);
    w[4] = f2bf(v1[0]); w[5] = f2bf(v1[1]); w[6] = f2bf(v1[2]); w[7] = f2bf(v1[3]);
    *(ushort8*)&dst[i * 8] = w;
}

// ---------------------------------------------------------------------------
// Kernel 0b: x f32 [b][c][p] -> xT bf16 [b][p][c]   (tiled 64x64 transpose)
// ---------------------------------------------------------------------------
__global__ __launch_bounds__(256) void cvt_xT_kernel(
        const float* __restrict__ x, ushort_t* __restrict__ xT) {
    const int b  = blockIdx.z;
    const int c0 = blockIdx.y * 64;
    const int p0 = blockIdx.x * 64;
    __shared__ ushort_t tile[64 * 72];

    const int tid = threadIdx.x;
    {   // load + convert: each thread 16 floats of one c-row
        int r = tid >> 2, pc = (tid & 3) * 16;
        const float* src = &x[((size_t)b * DIM + c0 + r) * HWN + p0 + pc];
        f32x4 v0 = *(const f32x4*)&src[0];
        f32x4 v1 = *(const f32x4*)&src[4];
        f32x4 v2 = *(const f32x4*)&src[8];
        f32x4 v3 = *(const f32x4*)&src[12];
        ushort8 w0, w1;
        w0[0]=f2bf(v0[0]); w0[1]=f2bf(v0[1]); w0[2]=f2bf(v0[2]); w0[3]=f2bf(v0[3]);
        w0[4]=f2bf(v1[0]); w0[5]=f2bf(v1[1]); w0[6]=f2bf(v1[2]); w0[7]=f2bf(v1[3]);
        w1[0]=f2bf(v2[0]); w1[1]=f2bf(v2[1]); w1[2]=f2bf(v2[2]); w1[3]=f2bf(v2[3]);
        w1[4]=f2bf(v3[0]); w1[5]=f2bf(v3[1]); w1[6]=f2bf(v3[2]); w1[7]=f2bf(v3[3]);
        *(ushort8*)&tile[r * 72 + pc]     = w0;
        *(ushort8*)&tile[r * 72 + pc + 8] = w1;
    }
    __syncthreads();
    {   // write transposed: each thread 16 c-values of one p-row
        int p = tid >> 2, cc = (tid & 3) * 16;
        ushort8 w0, w1;
        #pragma unroll
        for (int j = 0; j < 8; ++j) {
            w0[j] = tile[(cc + j) * 72 + p];
            w1[j] = tile[(cc + 8 + j) * 72 + p];
        }
        ushort_t* dst = &xT[((size_t)b * HWN + p0 + p) * DIM + c0 + cc];
        *(ushort8*)&dst[0] = w0;
        *(ushort8*)&dst[8] = w1;
    }
}

// ---------------------------------------------------------------------------
// Kernel 0c: wkv f32 [o2][c][di][dj] -> wkvT bf16 [o2][(di*2+dj)*512 + c]
// ---------------------------------------------------------------------------
__global__ __launch_bounds__(256) void cvt_wkvT_kernel(
        const float* __restrict__ wkv, ushort_t* __restrict__ wkvT) {
    int i = blockIdx.x * 256 + threadIdx.x;     // (o2, c) pair
    if (i >= 1024 * 512) return;
    int o2 = i >> 9, c = i & 511;
    f32x4 v = *(const f32x4*)&wkv[(size_t)i * 4];  // the 4 q values for this (o2,c)
    #pragma unroll
    for (int q = 0; q < 4; ++q)
        wkvT[(size_t)o2 * KKV + q * 512 + c] = f2bf(v[q]);
}

// ---------------------------------------------------------------------------
// Kernel 1: Q projection, m97 structure (128x128 tile, BK=32, global_load_lds).
// Qs[b][o][p] = (0.125*log2e) * sum_c Wq[o][c] * X[c][p]
// ---------------------------------------------------------------------------
__global__ __launch_bounds__(256) void qproj_kernel(
        const ushort_t* __restrict__ xT, const ushort_t* __restrict__ wqb,
        ushort_t* __restrict__ qs) {
    const int b  = blockIdx.z;
    const int m0 = blockIdx.y * 128;
    const int n0 = blockIdx.x * 128;

    __shared__ ushort_t ldsA[128 * 32];
    __shared__ ushort_t ldsB[128 * 32];

    const int tid  = threadIdx.x;
    const int wave = tid >> 6;
    const int lane = tid & 63;
    const int l15  = lane & 15;
    const int quad = lane >> 4;
    const int wm   = (wave >> 1) * 64;
    const int wn   = (wave & 1) * 64;

    // staging: wave covers 32 rows (2 instrs of 16 rows x 4 chunks)
    const int srow = wave * 32 + (lane >> 2);
    const int schk = (lane & 3) * 8;
    const ushort_t* asrc = &wqb[(m0 + srow) * DIM + schk];
    const ushort_t* bsrc = &xT[((size_t)b * HWN + n0 + srow) * DIM + schk];
    ushort_t* adst = &ldsA[wave * 1024];
    ushort_t* bdst = &ldsB[wave * 1024];

    f32x4 zero = {0.f, 0.f, 0.f, 0.f};
    f32x4 acc[4][4];
    #pragma unroll
    for (int i = 0; i < 4; ++i)
        #pragma unroll
        for (int j = 0; j < 4; ++j) acc[i][j] = zero;

    for (int k0 = 0; k0 < DIM; k0 += 32) {
        gload_lds16(asrc + k0,            adst);
        gload_lds16(asrc + 16 * DIM + k0, adst + 512);
        gload_lds16(bsrc + k0,            bdst);
        gload_lds16(bsrc + 16 * DIM + k0, bdst + 512);
        __syncthreads();
        kstep_mfma(ldsA, ldsB, wm, wn, l15, quad, acc);
        __syncthreads();
    }

    #pragma unroll
    for (int i = 0; i < 4; ++i)
        #pragma unroll
        for (int j = 0; j < 4; ++j)
            #pragma unroll
            for (int r = 0; r < 4; ++r) {
                int m = m0 + wm + i * 16 + quad * 4 + r;
                int n = n0 + wn + j * 16 + l15;
                qs[((size_t)b * DIM + m) * HWN + n] =
                    f2bf(acc[i][j][r] * (0.125f * LOG2E));
            }
}

// ---------------------------------------------------------------------------
// Kernel 2: KV conv-GEMM, m97 structure.  A = wkvT [1024][2048],
// B = im2col-gathered xT rows, per-lane global source for global_load_lds.
// m0 < 512 -> K, transposed epilogue through reused LDS; else V direct.
// ---------------------------------------------------------------------------
__global__ __launch_bounds__(256) void kv_kernel(
        const ushort_t* __restrict__ xT, const ushort_t* __restrict__ wkvT,
        ushort_t* __restrict__ ks, ushort_t* __restrict__ vt) {
    const int b  = blockIdx.z;
    const int m0 = blockIdx.y * 128;
    const int j0 = blockIdx.x * 128;

    __shared__ ushort_t sh[128 * 72];      // 18 KB: ldsA+ldsB overlay cbuf
    ushort_t* ldsA = sh;
    ushort_t* ldsB = sh + 4096;

    const int tid  = threadIdx.x;
    const int wave = tid >> 6;
    const int lane = tid & 63;
    const int l15  = lane & 15;
    const int quad = lane >> 4;
    const int wm   = (wave >> 1) * 64;
    const int wn   = (wave & 1) * 64;

    const int srow = wave * 32 + (lane >> 2);
    const int schk = (lane & 3) * 8;
    const int jr0 = j0 + srow, jr1 = jr0 + 16;
    const int y0 = jr0 >> 5, x0 = jr0 & 31;
    const int y1 = jr1 >> 5, x1 = jr1 & 31;

    const ushort_t* asrc = &wkvT[(size_t)(m0 + srow) * KKV + schk];
    ushort_t* adst = &ldsA[wave * 1024];
    ushort_t* bdst = &ldsB[wave * 1024];

    f32x4 zero = {0.f, 0.f, 0.f, 0.f};
    f32x4 acc[4][4];
    #pragma unroll
    for (int i = 0; i < 4; ++i)
        #pragma unroll
        for (int j = 0; j < 4; ++j) acc[i][j] = zero;

    for (int q = 0; q < 4; ++q) {
        const int di = q >> 1, dj = q & 1;
        const ushort_t* b0 =
            &xT[((size_t)b * HWN + (2 * y0 + di) * 64 + 2 * x0 + dj) * DIM + schk];
        const ushort_t* b1 =
            &xT[((size_t)b * HWN + (2 * y1 + di) * 64 + 2 * x1 + dj) * DIM + schk];
        const ushort_t* aq = asrc + q * 512;
        for (int kc = 0; kc < 512; kc += 32) {
            gload_lds16(aq + kc,                    adst);
            gload_lds16(aq + 16 * KKV + kc,         adst + 512);
            gload_lds16(b0 + kc,                    bdst);
            gload_lds16(b1 + kc,                    bdst + 512);
            __syncthreads();
            kstep_mfma(ldsA, ldsB, wm, wn, l15, quad, acc);
            __syncthreads();
        }
    }

    if (m0 < DIM) {
        // K half: tile spans heads h0, h0+1.  Two transpose passes through sh.
        const int h0 = m0 >> 6;
        #pragma unroll
        for (int mh = 0; mh < 2; ++mh) {
            if ((wave >> 1) == mh) {
                #pragma unroll
                for (int i = 0; i < 4; ++i)
                    #pragma unroll
                    for (int j = 0; j < 4; ++j)
                        #pragma unroll
                        for (int r = 0; r < 4; ++r) {
                            int mloc = i * 16 + quad * 4 + r;      // 0..63 (= d)
                            int n    = wn + j * 16 + l15;          // 0..127
                            sh[n * 72 + mloc] = f2bf(acc[i][j][r]);
                        }
            }
            __syncthreads();
            {   // copy out: thread -> 32 d-values of one token row
                int n = tid >> 1, doff = (tid & 1) * 32;
                ushort8 u0 = *(const ushort8*)&sh[n * 72 + doff];
                ushort8 u1 = *(const ushort8*)&sh[n * 72 + doff + 8];
                ushort8 u2 = *(const ushort8*)&sh[n * 72 + doff + 16];
                ushort8 u3 = *(const ushort8*)&sh[n * 72 + doff + 24];
                ushort_t* dst =
                    &ks[(((size_t)b * HEADS + h0 + mh) * KVN + j0 + n) * HD + doff];
                *(ushort8*)&dst[0]  = u0;
                *(ushort8*)&dst[8]  = u1;
                *(ushort8*)&dst[16] = u2;
                *(ushort8*)&dst[24] = u3;
            }
            __syncthreads();
        }
    } else {
        #pragma unroll
        for (int i = 0; i < 4; ++i)
            #pragma unroll
            for (int j = 0; j < 4; ++j)
                #pragma unroll
                for (int r = 0; r < 4; ++r) {
                    int mfull = m0 - DIM + wm + i * 16 + quad * 4 + r;
                    int h  = mfull >> 6, dd = mfull & 63;
                    int n  = wn + j * 16 + l15;
                    vt[(((size_t)b * HEADS + h) * HD + dd) * KVN + j0 + n] =
                        f2bf(acc[i][j][r]);
                }
    }
}

// ---------------------------------------------------------------------------
// Kernel 3: attention — unchanged from round 2.
// ---------------------------------------------------------------------------
__global__ __launch_bounds__(256, 2) void attn_kernel(
        const ushort_t* __restrict__ qs,   // [b][c][p], pre-scaled by 0.125*log2e
        const ushort_t* __restrict__ ks,   // [b][h][j][d]
        const ushort_t* __restrict__ vt,   // [b][h][d][j]
        ushort_t* __restrict__ ao) {       // [b][i][c]
    const int b = blockIdx.z, h = blockIdx.y;
    const int tid = threadIdx.x, wave = tid >> 6, lane = tid & 63;
    const int l15 = lane & 15, quad = lane >> 4;
    const int s7  = l15 & 7;
    const int iw = blockIdx.x * 256 + wave * 64;

    __shared__ ushort_t ldsK[2][64 * 64];
    __shared__ ushort_t ldsV[2][64 * 64];

    const ushort_t* Kh = &ks[((size_t)b * HEADS + h) * (KVN * HD)];
    const ushort_t* Vh = &vt[((size_t)b * HEADS + h) * (HD * KVN)];

    const int srow = wave * 8 + (lane >> 3);
    const int schk = (lane & 7) ^ (lane >> 3);
    const ushort_t* kp0 = Kh + srow * HD + schk * 8;
    const ushort_t* kp1 = Kh + (srow + 32) * HD + schk * 8;
    const ushort_t* vp0 = Vh + (size_t)srow * KVN + schk * 8;
    const ushort_t* vp1 = Vh + (size_t)(srow + 32) * KVN + schk * 8;

    bf16x8 bq[4][2];
    #pragma unroll
    for (int ih = 0; ih < 4; ++ih)
        #pragma unroll
        for (int kk = 0; kk < 2; ++kk) {
            ushort8 t;
            #pragma unroll
            for (int j = 0; j < 8; ++j) {
                int c = h * HD + kk * 32 + quad * 8 + j;
                int p = iw + ih * 16 + l15;
                t[j] = qs[((size_t)b * DIM + c) * HWN + p];
            }
            bq[ih][kk] = *(bf16x8*)&t;
        }

    f32x4 zero = {0.f, 0.f, 0.f, 0.f};
    f32x4 o[4][4];
    #pragma unroll
    for (int ih = 0; ih < 4; ++ih)
        #pragma unroll
        for (int nt = 0; nt < 4; ++nt) o[ih][nt] = zero;
    float ssum[4] = {0.f, 0.f, 0.f, 0.f};

    gload_lds16(kp0, &ldsK[0][wave * 512]);
    gload_lds16(kp1, &ldsK[0][wave * 512 + 2048]);
    gload_lds16(vp0, &ldsV[0][wave * 512]);
    gload_lds16(vp1, &ldsV[0][wave * 512 + 2048]);
    asm volatile("s_waitcnt vmcnt(0)" ::: "memory");
    __syncthreads();

    for (int t = 0; t < 16; ++t) {
        const int cur = t & 1;
        if (t < 15) {
            const int jn = (t + 1) * 64;
            gload_lds16(kp0 + jn * HD, &ldsK[cur ^ 1][wave * 512]);
            gload_lds16(kp1 + jn * HD, &ldsK[cur ^ 1][wave * 512 + 2048]);
            gload_lds16(vp0 + jn,      &ldsV[cur ^ 1][wave * 512]);
            gload_lds16(vp1 + jn,      &ldsV[cur ^ 1][wave * 512 + 2048]);
        }

        unsigned P2[4][4][2];
        #pragma unroll
        for (int nt = 0; nt < 4; ++nt) {
            const ushort_t* kb = &ldsK[cur][(nt * 16 + l15) * 64];
            bf16x8 bk0 = *(const bf16x8*)&kb[(quad ^ s7) * 8];
            bf16x8 bk1 = *(const bf16x8*)&kb[((quad + 4) ^ s7) * 8];
            #pragma unroll
            for (int ih = 0; ih < 4; ++ih) {
                f32x4 s = zero;
                s = __builtin_amdgcn_mfma_f32_16x16x32_bf16(bk0, bq[ih][0], s, 0, 0, 0);
                s = __builtin_amdgcn_mfma_f32_16x16x32_bf16(bk1, bq[ih][1], s, 0, 0, 0);
                float p0 = __builtin_amdgcn_exp2f(s[0]);
                float p1 = __builtin_amdgcn_exp2f(s[1]);
                float p2 = __builtin_amdgcn_exp2f(s[2]);
                float p3 = __builtin_amdgcn_exp2f(s[3]);
                ssum[ih] += (p0 + p1) + (p2 + p3);
                P2[ih][nt][0] = cvtpk(p0, p1);
                P2[ih][nt][1] = cvtpk(p2, p3);
            }
        }

        #pragma unroll
        for (int ih = 0; ih < 4; ++ih)
            #pragma unroll
            for (int bh = 0; bh < 2; ++bh)
                #pragma unroll
                for (int rp = 0; rp < 2; ++rp) {
                    pl32swap(P2[ih][bh * 2][rp], P2[ih][bh * 2 + 1][rp]);
                    pl16swap(P2[ih][bh * 2][rp], P2[ih][bh * 2 + 1][rp]);
                }
        bf16x8 bp[4][2];
        #pragma unroll
        for (int ih = 0; ih < 4; ++ih) {
            bp[ih][0] = frag4(P2[ih][0][0], P2[ih][0][1], P2[ih][1][0], P2[ih][1][1]);
            bp[ih][1] = frag4(P2[ih][2][0], P2[ih][2][1], P2[ih][3][0], P2[ih][3][1]);
        }

        #pragma unroll
        for (int nt = 0; nt < 4; ++nt) {
            const ushort_t* vb = &ldsV[cur][(nt * 16 + l15) * 64];
            bf16x8 bv0 = *(const bf16x8*)&vb[(quad ^ s7) * 8];
            bf16x8 bv1 = *(const bf16x8*)&vb[((quad + 4) ^ s7) * 8];
            #pragma unroll
            for (int ih = 0; ih < 4; ++ih) {
                o[ih][nt] = __builtin_amdgcn_mfma_f32_16x16x32_bf16(bv0, bp[ih][0], o[ih][nt], 0, 0, 0);
                o[ih][nt] = __builtin_amdgcn_mfma_f32_16x16x32_bf16(bv1, bp[ih][1], o[ih][nt], 0, 0, 0);
            }
        }

        asm volatile("s_waitcnt vmcnt(0)" ::: "memory");
        __syncthreads();
    }

    #pragma unroll
    for (int ih = 0; ih < 4; ++ih) {
        float tsum = ssum[ih];
        tsum += __shfl_xor(tsum, 16);
        tsum += __shfl_xor(tsum, 32);
        float invl = 1.0f / tsum;
        int i = iw + ih * 16 + l15;
        ushort_t* dst = &ao[((size_t)b * HWN + i) * DIM + h * HD];
        #pragma unroll
        for (int nt = 0; nt < 4; ++nt) {
            unsigned d0 = cvtpk(o[ih][nt][0] * invl, o[ih][nt][1] * invl);
            unsigned d1 = cvtpk(o[ih][nt][2] * invl, o[ih][nt][3] * invl);
            uint2v w; w[0] = d0; w[1] = d1;
            *(uint2v*)&dst[nt * 16 + quad * 4] = w;
        }
    }
}

// ---------------------------------------------------------------------------
// Kernel 4: output projection, m97 structure.
// out[b][o][p] = sum_c Wout[o][c] * AO[b][p][c]   (f32 output)
// ---------------------------------------------------------------------------
__global__ __launch_bounds__(256) void outproj_kernel(
        const ushort_t* __restrict__ ao, const ushort_t* __restrict__ woutb,
        float* __restrict__ out) {
    const int b  = blockIdx.z;
    const int m0 = blockIdx.y * 128;
    const int n0 = blockIdx.x * 128;

    __shared__ ushort_t ldsA[128 * 32];
    __shared__ ushort_t ldsB[128 * 32];

    const int tid  = threadIdx.x;
    const int wave = tid >> 6;
    const int lane = tid & 63;
    const int l15  = lane & 15;
    const int quad = lane >> 4;
    const int wm   = (wave >> 1) * 64;
    const int wn   = (wave & 1) * 64;

    const int srow = wave * 32 + (lane >> 2);
    const int schk = (lane & 3) * 8;
    const ushort_t* asrc = &woutb[(m0 + srow) * DIM + schk];
    const ushort_t* bsrc = &ao[((size_t)b * HWN + n0 + srow) * DIM + schk];
    ushort_t* adst = &ldsA[wave * 1024];
    ushort_t* bdst = &ldsB[wave * 1024];

    f32x4 zero = {0.f, 0.f, 0.f, 0.f};
    f32x4 acc[4][4];
    #pragma unroll
    for (int i = 0; i < 4; ++i)
        #pragma unroll
        for (int j = 0; j < 4; ++j) acc[i][j] = zero;

    for (int k0 = 0; k0 < DIM; k0 += 32) {
        gload_lds16(asrc + k0,            adst);
        gload_lds16(asrc + 16 * DIM + k0, adst + 512);
        gload_lds16(bsrc + k0,            bdst);
        gload_lds16(bsrc + 16 * DIM + k0, bdst + 512);
        __syncthreads();
        kstep_mfma(ldsA, ldsB, wm, wn, l15, quad, acc);
        __syncthreads();
    }

    #pragma unroll
    for (int i = 0; i < 4; ++i)
        #pragma unroll
        for (int j = 0; j < 4; ++j)
            #pragma unroll
            for (int r = 0; r < 4; ++r) {
                int m = m0 + wm + i * 16 + quad * 4 + r;
                int n = n0 + wn + j * 16 + l15;
                out[((size_t)b * DIM + m) * HWN + n] = acc[i][j][r];
            }
}

// ---------------------------------------------------------------------------
extern "C" void kernel_launch(void* const* d_in, const int* in_sizes, int n_in,
                              void* d_out, int out_size, void* d_ws, size_t ws_size,
                              hipStream_t stream) {
    const float* x    = (const float*)d_in[0];  // [4][512][64][64] f32
    const float* wq   = (const float*)d_in[1];  // [512][512] f32
    const float* wkv  = (const float*)d_in[2];  // [1024][512][2][2] f32
    const float* wout = (const float*)d_in[3];  // [512][512] f32
    float* out = (float*)d_out;                 // [4][512][64][64] f32

    char* ws = (char*)d_ws;
    ushort_t* xT    = (ushort_t*)(ws);               // 16.78 MB  [b][p][c]
    ushort_t* qsb   = (ushort_t*)(ws + 16777216);    // 16.78 MB  [b][c][p]
    ushort_t* ksb   = (ushort_t*)(ws + 33554432);    //  4.19 MB  [b][h][j][d]
    ushort_t* vtb   = (ushort_t*)(ws + 37748736);    //  4.19 MB  [b][h][d][j]
    ushort_t* aob   = (ushort_t*)(ws + 41943040);    // 16.78 MB  [b][i][c]
    ushort_t* wqb   = (ushort_t*)(ws + 58720256);    //  0.52 MB
    ushort_t* wkvT  = (ushort_t*)(ws + 59244544);    //  4.19 MB  [o2][(q,c)]
    ushort_t* woutb = (ushort_t*)(ws + 63438848);    //  0.52 MB

    cvt_xT_kernel  <<<dim3(64, 8, 4), 256, 0, stream>>>(x, xT);
    cvt_kernel     <<<dim3(128),      256, 0, stream>>>(wq, wqb, 32768);
    cvt_wkvT_kernel<<<dim3(2048),     256, 0, stream>>>(wkv, wkvT);
    cvt_kernel     <<<dim3(128),      256, 0, stream>>>(wout, woutb, 32768);

    qproj_kernel  <<<dim3(32, 4, 4),  256, 0, stream>>>(xT, wqb, qsb);
    kv_kernel     <<<dim3(8, 8, 4),   256, 0, stream>>>(xT, wkvT, ksb, vtb);
    attn_kernel   <<<dim3(16, 8, 4),  256, 0, stream>>>(qsb, ksb, vtb, aob);
    outproj_kernel<<<dim3(32, 4, 4),  256, 0, stream>>>(aob, woutb, out);
}